// Round 13
// baseline (367.383 us; speedup 1.0000x reference)
//
#include <hip/hip_runtime.h>
#include <cstdint>
#include <cstddef>

#define I_DIM   2048
#define O_DIM   1024
#define TB      10
#define ITERS   1024          // T / TB
#define I4      512           // I_DIM / 4
#define LISTMAX 320           // max active batches/neuron (mean 187, sd 12.4)
#define LOG2E   1.44269504088896340736f
#define LN2     0.69314718055994530942f

// ---------------------------------------------------------------------------
// Kernel A: one block per time-batch t. float4 spike reads; writes t-major
// mask_t[t][o] as ushort4 (fully coalesced) and toss[t] via block reduction.
// ---------------------------------------------------------------------------
__global__ __launch_bounds__(256)
void prep_kernel(const float* __restrict__ spk,
                 unsigned short* __restrict__ mask_t, // [ITERS][O]
                 float* __restrict__ toss) {          // [ITERS]
    const int t   = blockIdx.x;
    const int tid = threadIdx.x;
    const float4* base4 = (const float4*)(spk + (size_t)t * TB * O_DIM);
    float    s[4] = {0.f, 0.f, 0.f, 0.f};
    unsigned m[4] = {0u, 0u, 0u, 0u};
#pragma unroll
    for (int i = 0; i < TB; ++i) {
        float4 v = base4[(size_t)i * (O_DIM / 4) + tid];
        s[0] += v.x; if (v.x != 0.f) m[0] |= (1u << i);
        s[1] += v.y; if (v.y != 0.f) m[1] |= (1u << i);
        s[2] += v.z; if (v.z != 0.f) m[2] |= (1u << i);
        s[3] += v.w; if (v.w != 0.f) m[3] |= (1u << i);
    }
    ushort4 mv = make_ushort4((unsigned short)m[0], (unsigned short)m[1],
                              (unsigned short)m[2], (unsigned short)m[3]);
    ((ushort4*)(mask_t + (size_t)t * O_DIM))[tid] = mv;

    __shared__ float red[256];
    red[tid] = s[0] + s[1] + s[2] + s[3];
    __syncthreads();
    for (int st = 128; st > 0; st >>= 1) {
        if (tid < st) red[tid] += red[tid + st];
        __syncthreads();
    }
    if (tid == 0) toss[t] = red[0];
}

// ---------------------------------------------------------------------------
// Kernel B: compact + bias, fused. One wave per neuron (4/block, 256 blocks).
// Wave scans its neuron's masks (strided reads, L2-hot), ballot-compacts into
// list[o][k] = (t<<10)|mask (t-ordered, one zero entry appended), and stashes
// the masks in LDS. Then lane 0 runs the serial 1024-step bias recurrence.
// ---------------------------------------------------------------------------
__global__ __launch_bounds__(256)
void compact_bias_kernel(const unsigned short* __restrict__ mask_t, // [ITERS][O]
                         const float* __restrict__ toss,
                         const float* __restrict__ Nk,
                         const float* __restrict__ b_in,
                         unsigned int* __restrict__ lists,   // [O][LISTMAX]
                         int* __restrict__ counts,           // [O]
                         float* __restrict__ b_out) {
    __shared__ unsigned short s_masks[4][ITERS];  // 8 KB
    __shared__ float          s_toss[ITERS];      // 4 KB
    __shared__ float          red[256];
    const int tid  = threadIdx.x;
    const int w    = tid >> 6;
    const int lane = tid & 63;
    const int o    = blockIdx.x * 4 + w;

    float s = 0.f;
    for (int i = tid; i < O_DIM; i += 256) s += Nk[i];
    red[tid] = s;
    __syncthreads();
    for (int st = 128; st > 0; st >>= 1) {
        if (tid < st) red[tid] += red[tid + st];
        __syncthreads();
    }
    const float snk0 = red[0];
    for (int i = tid; i < ITERS; i += 256) s_toss[i] = toss[i];
    __syncthreads();

    unsigned int* list = lists + (size_t)o * LISTMAX;
    int cnt = 0;
    for (int base = 0; base < ITERS; base += 64) {
        unsigned int m = mask_t[(size_t)(base + lane) * O_DIM + o];
        s_masks[w][base + lane] = (unsigned short)m;
        bool act = (m != 0u);
        unsigned long long b = __ballot(act);
        int pre = __popcll(b & ((1ull << lane) - 1ull));
        if (act && cnt + pre < LISTMAX)
            list[cnt + pre] = ((unsigned)(base + lane) << 10) | m;
        cnt += __popcll(b);
    }
    if (lane == 0) {
        int c = cnt < LISTMAX ? cnt : LISTMAX;
        if (c < LISTMAX) list[c] = 0u;             // sentinel for depth-2 prefetch
        counts[o] = c;
        // serial bias chain (exp2 domain), masks/toss from LDS
        float bs  = b_in[o] * LOG2E;
        float snk = snk0;
        for (int t = 0; t < ITERS; ++t) {
            float tos_t  = (float)__popc((unsigned)s_masks[w][t]);
            float toss_t = s_toss[t];
            float inv = __builtin_amdgcn_rcpf(snk) * LOG2E;  // snk BEFORE update
            bs += inv * ((exp2f(-bs) * tos_t - 1.0f) * toss_t);
            snk += toss_t;
        }
        b_out[o] = bs * LN2;
    }
}

// ---------------------------------------------------------------------------
// Kernel C: weight rows, f32 loads, depth-2 prefetch: entry k+1's first-spike
// row load is issued before entry k's update, bounding in-flight rows to ~2
// per wave (r11's depth-8 thrashed L2; r12's f16 unpack was VALU-bound).
// 2 blocks/neuron, 2048 blocks = 8 blocks/CU. exp2-domain weights.
// ---------------------------------------------------------------------------
__global__ __launch_bounds__(256)
void stdp_main_kernel(const float* __restrict__ psp,
                      const float* __restrict__ w_in,
                      const float* __restrict__ Nk,
                      const unsigned int* __restrict__ lists,
                      const int* __restrict__ counts,
                      float* __restrict__ w_out) {
    const int bid   = blockIdx.x;
    const int o     = bid >> 1;
    const int half  = bid & 1;
    const int tid   = threadIdx.x;
    const int lane4 = half * 256 + tid;            // float4 index within the row

    const float4* __restrict__ psp4 = (const float4*)psp + lane4;
    float4 w0 = ((const float4*)w_in)[(size_t)o * I4 + lane4];
    float4 a  = make_float4(w0.x * LOG2E, w0.y * LOG2E, w0.z * LOG2E, w0.w * LOG2E);
    float  nk = Nk[o];

    __shared__ unsigned int s_list[LISTMAX];
    const int count = counts[o];                   // uniform
    const unsigned int* lp = lists + (size_t)o * LISTMAX;
    const int stage = count + 1 < LISTMAX ? count + 1 : LISTMAX;  // incl. sentinel
    if (tid < stage)       s_list[tid]       = lp[tid];
    if (tid + 256 < stage) s_list[tid + 256] = lp[tid + 256];
    __syncthreads();

    auto load_first = [&](unsigned e) -> float4 {  // first-spike row of entry e
        unsigned m = e & 1023u;
        if (m) {
            unsigned r = (e >> 10) * TB + (unsigned)(__ffs(m) - 1);
            return psp4[(size_t)r << 9];           // r * I4
        }
        return make_float4(0.f, 0.f, 0.f, 0.f);
    };

    if (count > 0) {
        unsigned e0 = s_list[0];
        float4   p0 = load_first(e0);
        for (int k = 0; k < count; ++k) {
            const unsigned e1 = s_list[k + 1];     // sentinel at [count]
            const float4   p1 = load_first(e1);    // issue next load early
            // ---- update entry e0 with first-row p0 ----
            unsigned m = e0 & 1023u;
            float4 c = p0;
            unsigned rem = m ? (m & (m - 1)) : 0u; // spikes beyond first (rare)
            while (rem) {
                unsigned r = (e0 >> 10) * TB + (unsigned)(__ffs(rem) - 1);
                rem &= rem - 1;
                const float4 q = psp4[(size_t)r << 9];
                c.x += q.x; c.y += q.y; c.z += q.z; c.w += q.w;
            }
            const float tos_t = (float)__popc(m);
            const float inv   = __builtin_amdgcn_rcpf(nk) * LOG2E;  // nk BEFORE
            nk += tos_t;
            a.x += inv * (c.x * exp2f(-a.x) - tos_t);
            a.y += inv * (c.y * exp2f(-a.y) - tos_t);
            a.z += inv * (c.z * exp2f(-a.z) - tos_t);
            a.w += inv * (c.w * exp2f(-a.w) - tos_t);
            e0 = e1; p0 = p1;
        }
    }

    float4 ov = make_float4(a.x * LN2, a.y * LN2, a.z * LN2, a.w * LN2);
    ((float4*)w_out)[(size_t)o * I4 + lane4] = ov;
}

// ---------------------------------------------------------------------------
extern "C" void kernel_launch(void* const* d_in, const int* in_sizes, int n_in,
                              void* d_out, int out_size, void* d_ws, size_t ws_size,
                              hipStream_t stream) {
    const float* psp = (const float*)d_in[0];   // (T, I)
    const float* spk = (const float*)d_in[1];   // (T, O)
    const float* w   = (const float*)d_in[2];   // (O, I)
    const float* b   = (const float*)d_in[3];   // (O,)
    const float* Nk  = (const float*)d_in[4];   // (O, 1)

    float* w_out = (float*)d_out;
    float* b_out = (float*)d_out + (size_t)O_DIM * I_DIM;

    char* ws = (char*)d_ws;
    unsigned short* mask_t = (unsigned short*)ws;                              // 2 MB
    unsigned int*   lists  = (unsigned int*)(ws + (size_t)ITERS * O_DIM * 2);  // 1.31 MB
    int*            counts = (int*)(ws + (size_t)ITERS * O_DIM * 2
                                       + (size_t)O_DIM * LISTMAX * 4);         // 4 KB
    float*          toss   = (float*)(counts + O_DIM);                         // 4 KB

    prep_kernel<<<ITERS, 256, 0, stream>>>(spk, mask_t, toss);
    compact_bias_kernel<<<O_DIM / 4, 256, 0, stream>>>(mask_t, toss, Nk, b,
                                                       lists, counts, b_out);
    stdp_main_kernel<<<2 * O_DIM, 256, 0, stream>>>(psp, w, Nk, lists, counts, w_out);
}

// Round 14
// 218.989 us; speedup vs baseline: 1.6776x; 1.6776x over previous
//
#include <hip/hip_runtime.h>
#include <cstdint>
#include <cstddef>

#define I_DIM   2048
#define O_DIM   1024
#define TB      10
#define ITERS   1024          // T / TB
#define I4      512           // I_DIM / 4
#define LISTMAX 320           // max active batches/neuron (mean 187, sd 12.4)
#define LSTRIDE (LISTMAX + 1) // +1 sentinel slot
#define LOG2E   1.44269504088896340736f
#define LN2     0.69314718055994530942f

// ---------------------------------------------------------------------------
// Kernel A: one block per time-batch t. float4 spike reads; o-major mask_T
// (coalesced-enough 2B strided stores, proven in r8/r12) + toss[t].
// ---------------------------------------------------------------------------
__global__ __launch_bounds__(256)
void prep_kernel(const float* __restrict__ spk,
                 unsigned short* __restrict__ mask_T, // [O][ITERS]
                 float* __restrict__ toss) {          // [ITERS]
    const int t   = blockIdx.x;
    const int tid = threadIdx.x;
    const float4* base4 = (const float4*)(spk + (size_t)t * TB * O_DIM);
    float    s[4] = {0.f, 0.f, 0.f, 0.f};
    unsigned m[4] = {0u, 0u, 0u, 0u};
#pragma unroll
    for (int i = 0; i < TB; ++i) {
        float4 v = base4[(size_t)i * (O_DIM / 4) + tid];
        s[0] += v.x; if (v.x != 0.f) m[0] |= (1u << i);
        s[1] += v.y; if (v.y != 0.f) m[1] |= (1u << i);
        s[2] += v.z; if (v.z != 0.f) m[2] |= (1u << i);
        s[3] += v.w; if (v.w != 0.f) m[3] |= (1u << i);
    }
#pragma unroll
    for (int j = 0; j < 4; ++j)
        mask_T[(size_t)(tid * 4 + j) * ITERS + t] = (unsigned short)m[j];
    __shared__ float red[256];
    red[tid] = s[0] + s[1] + s[2] + s[3];
    __syncthreads();
    for (int st = 128; st > 0; st >>= 1) {
        if (tid < st) red[tid] += red[tid + st];
        __syncthreads();
    }
    if (tid == 0) toss[t] = red[0];
}

// ---------------------------------------------------------------------------
// Kernel B: compaction + per-entry inv precompute. One wave per neuron.
// Ballot-compacts active batches into list[o][k] = {(t<<10)|mask, inv_k}
// where inv_k = rcp(nk_k)*LOG2E and nk_k = Nk + prefix-sum(tos) (exclusive),
// via a 64-lane shfl scan. Appends one zero sentinel.
// ---------------------------------------------------------------------------
__global__ __launch_bounds__(256)
void compact_kernel(const unsigned short* __restrict__ mask_T,
                    const float* __restrict__ Nk,
                    uint2* __restrict__ lists,          // [O][LSTRIDE]
                    int* __restrict__ counts) {         // [O]
    const int tid  = threadIdx.x;
    const int o    = blockIdx.x * 4 + (tid >> 6);
    const int lane = tid & 63;
    const unsigned short* row = mask_T + (size_t)o * ITERS;
    uint2* list = lists + (size_t)o * LSTRIDE;
    const float nk0 = Nk[o];
    int cnt = 0;       // active entries so far
    int tot = 0;       // cumulative tos so far (int, exact)
    for (int base = 0; base < ITERS; base += 64) {
        unsigned int m = row[base + lane];
        bool act = (m != 0u);
        int tos = __popc(m);
        // inclusive shfl scan of tos over the wave
        int v = tos;
#pragma unroll
        for (int d = 1; d < 64; d <<= 1) {
            int y = __shfl_up(v, d);
            if (lane >= d) v += y;
        }
        const int excl = v - tos;                  // exclusive prefix
        unsigned long long b = __ballot(act);
        int pre = __popcll(b & ((1ull << lane) - 1ull));
        if (act && cnt + pre < LISTMAX) {
            float nk_k = nk0 + (float)(tot + excl);
            float inv  = __builtin_amdgcn_rcpf(nk_k) * LOG2E;
            list[cnt + pre] = make_uint2(((unsigned)(base + lane) << 10) | m,
                                         __float_as_uint(inv));
        }
        cnt += __popcll(b);
        tot += __shfl(v, 63);                      // chunk total
    }
    if (lane == 0) {
        int c = cnt < LISTMAX ? cnt : LISTMAX;
        list[c] = make_uint2(0u, 0u);              // sentinel
        counts[o] = c;
    }
}

// ---------------------------------------------------------------------------
// Kernel C: bias chain, one thread per neuron; sumNk in-block; exp2 domain.
// ---------------------------------------------------------------------------
__global__ __launch_bounds__(256)
void bias_kernel(const unsigned short* __restrict__ mask_T,
                 const float* __restrict__ toss,
                 const float* __restrict__ Nk,
                 const float* __restrict__ b_in,
                 float* __restrict__ b_out) {
    __shared__ float s_toss[ITERS];
    __shared__ float red[256];
    const int tid = threadIdx.x;
    const int o   = blockIdx.x * 256 + tid;
    float s = 0.f;
    for (int i = tid; i < O_DIM; i += 256) s += Nk[i];
    red[tid] = s;
    __syncthreads();
    for (int st = 128; st > 0; st >>= 1) {
        if (tid < st) red[tid] += red[tid + st];
        __syncthreads();
    }
    float snk = red[0];
    for (int i = tid; i < ITERS; i += 256) s_toss[i] = toss[i];
    __syncthreads();

    float bs = b_in[o] * LOG2E;
    const uint4* row4 = (const uint4*)(mask_T + (size_t)o * ITERS);
    for (int blk = 0; blk < ITERS / 8; ++blk) {
        uint4 v = row4[blk];
        unsigned wds[4] = {v.x, v.y, v.z, v.w};
#pragma unroll
        for (int j = 0; j < 8; ++j) {
            unsigned m = (wds[j >> 1] >> ((j & 1) * 16)) & 0xFFFFu;
            float tos_t  = (float)__popc(m);
            float toss_t = s_toss[blk * 8 + j];
            float inv = __builtin_amdgcn_rcpf(snk) * LOG2E;  // snk BEFORE update
            bs += inv * ((exp2f(-bs) * tos_t - 1.0f) * toss_t);
            snk += toss_t;
        }
    }
    b_out[o] = bs * LN2;
}

// ---------------------------------------------------------------------------
// Kernel D: weight rows, XCD-partitioned segments. Row split into 8 segments
// of 256 floats; block bid handles segment s = bid%8 (= its XCD under the
// measured round-robin mapping) for neurons o = 2*(bid>>3)+wave. Segment-s
// psp data is only ever touched by XCD s -> fetched ~once, then L2-hot.
// Depth-2 row prefetch (safe now: drift window << 4MB L2 slice). Per-entry
// inv is precomputed, so the only serial chain left is `a` itself.
// ---------------------------------------------------------------------------
__global__ __launch_bounds__(128)
void stdp_main_kernel(const float* __restrict__ psp,
                      const float* __restrict__ w_in,
                      const uint2* __restrict__ lists,
                      const int* __restrict__ counts,
                      float* __restrict__ w_out) {
    const int bid  = blockIdx.x;
    const int seg  = bid & 7;
    const int wv   = threadIdx.x >> 6;
    const int lane = threadIdx.x & 63;
    const int o    = ((bid >> 3) << 1) | wv;
    const int lane4 = seg * 64 + lane;             // float4 index within the row

    const float4* __restrict__ psp4 = (const float4*)psp + lane4;
    float4 w0 = ((const float4*)w_in)[(size_t)o * I4 + lane4];
    float4 a  = make_float4(w0.x * LOG2E, w0.y * LOG2E, w0.z * LOG2E, w0.w * LOG2E);

    __shared__ uint2 s_list[2][LSTRIDE];
    const int count = counts[o];                   // uniform per wave
    const uint2* lp = lists + (size_t)o * LSTRIDE;
    for (int i = lane; i <= count; i += 64) s_list[wv][i] = lp[i];
    __syncthreads();

    auto load_first = [&](unsigned e) -> float4 {  // first-spike row of entry e
        unsigned m = e & 1023u;
        if (m) {
            unsigned r = (e >> 10) * TB + (unsigned)(__ffs(m) - 1);
            return psp4[(size_t)r << 9];           // r * I4
        }
        return make_float4(0.f, 0.f, 0.f, 0.f);
    };

    if (count > 0) {
        uint2  E0 = s_list[wv][0];
        float4 p0 = load_first(E0.x);
        for (int k = 0; k < count; ++k) {
            const uint2  E1 = s_list[wv][k + 1];   // sentinel at [count]
            const float4 p1 = load_first(E1.x);    // prefetch next row
            unsigned m = E0.x & 1023u;
            float4 c = p0;
            unsigned rem = m & (m - 1);            // spikes beyond first (rare)
            while (rem) {
                unsigned r = (E0.x >> 10) * TB + (unsigned)(__ffs(rem) - 1);
                rem &= rem - 1;
                const float4 q = psp4[(size_t)r << 9];
                c.x += q.x; c.y += q.y; c.z += q.z; c.w += q.w;
            }
            const float tos_t = (float)__popc(m);
            const float inv   = __uint_as_float(E0.y);   // rcp(nk)*LOG2E, precomputed
            a.x += inv * (c.x * exp2f(-a.x) - tos_t);
            a.y += inv * (c.y * exp2f(-a.y) - tos_t);
            a.z += inv * (c.z * exp2f(-a.z) - tos_t);
            a.w += inv * (c.w * exp2f(-a.w) - tos_t);
            E0 = E1; p0 = p1;
        }
    }

    float4 ov = make_float4(a.x * LN2, a.y * LN2, a.z * LN2, a.w * LN2);
    ((float4*)w_out)[(size_t)o * I4 + lane4] = ov;
}

// ---------------------------------------------------------------------------
extern "C" void kernel_launch(void* const* d_in, const int* in_sizes, int n_in,
                              void* d_out, int out_size, void* d_ws, size_t ws_size,
                              hipStream_t stream) {
    const float* psp = (const float*)d_in[0];   // (T, I)
    const float* spk = (const float*)d_in[1];   // (T, O)
    const float* w   = (const float*)d_in[2];   // (O, I)
    const float* b   = (const float*)d_in[3];   // (O,)
    const float* Nk  = (const float*)d_in[4];   // (O, 1)

    float* w_out = (float*)d_out;
    float* b_out = (float*)d_out + (size_t)O_DIM * I_DIM;

    char* ws = (char*)d_ws;
    unsigned short* mask_T = (unsigned short*)ws;                              // 2 MB
    uint2*          lists  = (uint2*)(ws + (size_t)O_DIM * ITERS * 2);         // 2.63 MB
    int*            counts = (int*)(ws + (size_t)O_DIM * ITERS * 2
                                       + (size_t)O_DIM * LSTRIDE * 8);         // 4 KB
    float*          toss   = (float*)(counts + O_DIM);                         // 4 KB

    prep_kernel<<<ITERS, 256, 0, stream>>>(spk, mask_T, toss);
    compact_kernel<<<O_DIM / 4, 256, 0, stream>>>(mask_T, Nk, lists, counts);
    stdp_main_kernel<<<8 * O_DIM / 2, 128, 0, stream>>>(psp, w, lists, counts, w_out);
    bias_kernel<<<O_DIM / 256, 256, 0, stream>>>(mask_T, toss, Nk, b, b_out);
}